// Round 12
// baseline (138.316 us; speedup 1.0000x reference)
//
#include <hip/hip_runtime.h>
#include <stdint.h>

#define HNUM 240
#define WNUM 1216
#define BNUM 4
#define HWN (HNUM * WNUM)
#define NPIX (BNUM * HWN)

#define TR 16                 /* tile rows */
#define TC 64                 /* tile cols */
#define RH 12                 /* halo radius */
#define LR (TR + 2 * RH + 1)  /* 41 LDS rows */
#define LC (TC + 2 * RH + 1)  /* 89 LDS cols used */
#define LCP 90                /* LDS col stride */
#define LDSN (LR * LCP)       /* 3690 */
#define PXJ 4                 /* px per thread */
#define TGR (HNUM / TR)       /* 15 */
#define TGC (WNUM / TC)       /* 19 */
#define NTILE (BNUM * TGR * TGC)  /* 1140 blocks */

union HCV { uint32_t u; _Float16 h[2]; };

__device__ __forceinline__ float fast_tanh(float x) {
    float ax = fabsf(x);
    float e  = __builtin_amdgcn_exp2f(ax * 2.885390081777927f);  // 2*log2(e)
    float t  = 1.0f - 2.0f * __builtin_amdgcn_rcpf(e + 1.0f);
    return copysignf(t, x);
}

// ---------------------------------------------------------------------------
// step 1 fused with meta build. Tile 16x64, halo 12, pred*conf staged in LDS.
// Thread mapping: row = tid>>4, cols = 4*(tid&15)..+3  -> float4 input loads.
// meta/px: 8 taps u32 (drow s8 | dcol s8 | qy u8 | qx u8) in tapsA/tapsB,
//          affaux u4 = {affs s8 x4, affs s8 x4, (aref|conf) fp16x2, dep f32}
// ---------------------------------------------------------------------------
__global__ __launch_bounds__(256) void nlspn_step1_lds(
    const float* __restrict__ aff_raw,
    const float* __restrict__ offset,
    const float* __restrict__ conf,
    const float* __restrict__ dep,
    const float* __restrict__ pred,
    const float* __restrict__ scale,
    _Float16* __restrict__ planeOut,
    uint4* __restrict__ tapsA,
    uint4* __restrict__ tapsB,
    uint4* __restrict__ affaux)
{
    __shared__ _Float16 tile[LDSN];

    int bid  = blockIdx.x;
    int b    = bid / (TGR * TGC);
    int rem  = bid - b * (TGR * TGC);
    int tr   = rem / TGC;
    int tc   = rem - tr * TGC;
    int tid  = (int)threadIdx.x;

    int row0 = tr * TR - RH;
    int col0 = tc * TC - RH;

    // ---- stage ff0 = pred*conf (zero outside image) ----
    for (int i = tid; i < LDSN; i += 256) {
        int lr = i / LCP;
        int lc = i - lr * LCP;
        int gr = row0 + lr;
        int gc = col0 + lc;
        float v = 0.f;
        if (lc < LC && gr >= 0 && gr < HNUM && gc >= 0 && gc < WNUM) {
            int pi = b * HWN + gr * WNUM + gc;
            v = pred[pi] * conf[pi];
        }
        tile[i] = (_Float16)v;
    }
    __syncthreads();

    float s    = scale[0];
    float invs = 1.0f / (s + 1e-8f);

    int r  = tid >> 4;            // 0..15 tile row
    int c4 = (tid & 15) << 2;     // first of 4 consecutive cols
    int h  = tr * TR + r;
    int w0 = tc * TC + c4;
    int hw0 = h * WNUM + w0;
    int p0  = b * HWN + hw0;

    // ---- vectorized input loads: 26 float4 ----
    const float* arb = aff_raw + (size_t)b * 8 * HWN + hw0;
    const float* ofb = offset  + (size_t)b * 16 * HWN + hw0;
    float4 ar4[8], oy4[8], ox4[8];
#pragma unroll
    for (int k = 0; k < 8; ++k) ar4[k] = *(const float4*)(arb + (size_t)k * HWN);
#pragma unroll
    for (int k = 0; k < 8; ++k) {
        oy4[k] = *(const float4*)(ofb + (size_t)(2 * k)     * HWN);
        ox4[k] = *(const float4*)(ofb + (size_t)(2 * k + 1) * HWN);
    }
    float4 cf4 = *(const float4*)(conf + p0);
    float4 dd4 = *(const float4*)(dep  + p0);

    float cfa[4] = {cf4.x, cf4.y, cf4.z, cf4.w};
    float dda[4] = {dd4.x, dd4.y, dd4.z, dd4.w};

#pragma unroll
    for (int jj = 0; jj < 4; ++jj) {
        int w  = w0 + jj;
        int p  = p0 + jj;

        // affinity normalization
        float aa[8];
        float asum = 0.f;
#pragma unroll
        for (int k = 0; k < 8; ++k) {
            float rv = (jj == 0) ? ar4[k].x : (jj == 1) ? ar4[k].y
                     : (jj == 2) ? ar4[k].z : ar4[k].w;
            float t = fast_tanh(rv) * invs;
            aa[k] = t;
            asum += fabsf(t);
        }
        float rden = 1.0f / fmaxf(asum + 1e-4f, 1.0f);
        float sm = 0.f;
#pragma unroll
        for (int k = 0; k < 8; ++k) { aa[k] *= rden; sm += aa[k]; }
        float aref = 1.0f - sm;

        // build taps + gather from LDS
        int cbase = (RH + r) * LCP + (RH + c4 + jj);
        float acc = aref * (float)tile[cbase];

        uint32_t tw[8];
#pragma unroll
        for (int k = 0; k < 8; ++k) {
            int k9 = (k < 4) ? k : k + 1;
            int dy = k9 / 3 - 1;
            int dx = k9 - (k9 / 3) * 3 - 1;
            float offy = (jj == 0) ? oy4[k].x : (jj == 1) ? oy4[k].y
                       : (jj == 2) ? oy4[k].z : oy4[k].w;
            float offx = (jj == 0) ? ox4[k].x : (jj == 1) ? ox4[k].y
                       : (jj == 2) ? ox4[k].z : ox4[k].w;
            float ys  = (float)(h + dy) + offy;
            float xs  = (float)(w + dx) + offx;
            float y0f = floorf(ys), x0f = floorf(xs);
            float wyf = ys - y0f,   wxf = xs - x0f;
            int drow = (int)y0f - h;
            int dcol = (int)x0f - w;
            uint32_t qy = (uint32_t)(wyf * 255.0f + 0.5f); if (qy > 255) qy = 255;
            uint32_t qx = (uint32_t)(wxf * 255.0f + 0.5f); if (qx > 255) qx = 255;
            int lr = RH + r + drow;
            int lc = RH + c4 + jj + dcol;
            if (lr < 0 || lr > LR - 2 || lc < 0 || lc > LC - 2) {
                drow = 0; dcol = 0; qy = 0; qx = 0; aa[k] = 0.f;
            }
            tw[k] = (uint32_t)(uint8_t)(int8_t)drow
                  | ((uint32_t)(uint8_t)(int8_t)dcol << 8)
                  | (qy << 16) | (qx << 24);

            int la = cbase + drow * LCP + dcol;
            float g00 = (float)tile[la];
            float g01 = (float)tile[la + 1];
            float g10 = (float)tile[la + LCP];
            float g11 = (float)tile[la + LCP + 1];
            float fwy = (float)qy * (1.0f / 255.0f);
            float fwx = (float)qx * (1.0f / 255.0f);
            float top = fmaf(fwx, g01 - g00, g00);
            float bot = fmaf(fwx, g11 - g10, g10);
            acc = fmaf(aa[k], fmaf(fwy, bot - top, top), acc);
        }

        tapsA[p] = make_uint4(tw[0], tw[1], tw[2], tw[3]);
        tapsB[p] = make_uint4(tw[4], tw[5], tw[6], tw[7]);

        // quantize affs to s8
        uint32_t pk[2] = {0u, 0u};
#pragma unroll
        for (int k = 0; k < 8; ++k) {
            int q = (int)floorf(aa[k] * 127.0f + 0.5f);
            q = (q < -127) ? -127 : ((q > 127) ? 127 : q);
            pk[k >> 2] |= ((uint32_t)(uint8_t)(int8_t)q) << (8 * (k & 3));
        }
        HCV cv;
        cv.h[0] = (_Float16)aref;
        cv.h[1] = (_Float16)cfa[jj];
        affaux[p] = make_uint4(pk[0], pk[1], cv.u, __float_as_uint(dda[jj]));

        float feat = (dda[jj] > 0.f) ? dda[jj] : acc;
        planeOut[p] = (_Float16)(feat * cfa[jj]);
    }
}

// ---------------------------------------------------------------------------
// propagation step: stage plane tile in LDS, 33 LDS gathers/px, meta streamed
// ---------------------------------------------------------------------------
template <bool LAST>
__global__ __launch_bounds__(256) void nlspn_prop_lds(
    const uint4* __restrict__ tapsA,
    const uint4* __restrict__ tapsB,
    const uint4* __restrict__ affaux,
    const _Float16* __restrict__ planeIn,
    _Float16* __restrict__ planeOut,
    float* __restrict__ out)
{
    __shared__ _Float16 tile[LDSN];

    int bid  = blockIdx.x;
    int b    = bid / (TGR * TGC);
    int rem  = bid - b * (TGR * TGC);
    int tr   = rem / TGC;
    int tc   = rem - tr * TGC;
    int tid  = (int)threadIdx.x;
    int lane = tid & 63;
    int wrow = tid >> 6;

    int row0 = tr * TR - RH;
    int col0 = tc * TC - RH;
    const _Float16* pb = planeIn + (size_t)b * HWN;

    for (int i = tid; i < LDSN; i += 256) {
        int lr = i / LCP;
        int lc = i - lr * LCP;
        int gr = row0 + lr;
        int gc = col0 + lc;
        _Float16 v = (_Float16)0.f;
        if (lc < LC && gr >= 0 && gr < HNUM && gc >= 0 && gc < WNUM)
            v = pb[gr * WNUM + gc];
        tile[i] = v;
    }
    __syncthreads();

#pragma unroll
    for (int j = 0; j < PXJ; ++j) {
        int rj = wrow * PXJ + j;
        int h  = tr * TR + rj;
        int w  = tc * TC + lane;
        int p  = b * HWN + h * WNUM + w;

        uint4 tA = tapsA[p];
        uint4 tB = tapsB[p];
        uint4 ax = affaux[p];

        // decode affs (s8)
        float af[8];
        int32_t vx = (int32_t)ax.x;
        int32_t vy = (int32_t)ax.y;
        af[0] = (float)((vx << 24) >> 24) * (1.0f / 127.0f);
        af[1] = (float)((vx << 16) >> 24) * (1.0f / 127.0f);
        af[2] = (float)((vx <<  8) >> 24) * (1.0f / 127.0f);
        af[3] = (float)( vx        >> 24) * (1.0f / 127.0f);
        af[4] = (float)((vy << 24) >> 24) * (1.0f / 127.0f);
        af[5] = (float)((vy << 16) >> 24) * (1.0f / 127.0f);
        af[6] = (float)((vy <<  8) >> 24) * (1.0f / 127.0f);
        af[7] = (float)( vy        >> 24) * (1.0f / 127.0f);

        HCV cv; cv.u = ax.z;
        float aref = (float)cv.h[0];
        float cf   = (float)cv.h[1];
        float dd   = __uint_as_float(ax.w);

        int cbase = (RH + rj) * LCP + (RH + lane);
        float acc = aref * (float)tile[cbase];

        uint32_t tm[8] = {tA.x, tA.y, tA.z, tA.w, tB.x, tB.y, tB.z, tB.w};
#pragma unroll
        for (int k = 0; k < 8; ++k) {
            uint32_t m = tm[k];
            int drow = (int)(int8_t)(m & 0xffu);
            int dcol = (int)(int8_t)((m >> 8) & 0xffu);
            float wy = (float)((m >> 16) & 0xffu) * (1.0f / 255.0f);
            float wx = (float)(m >> 24)           * (1.0f / 255.0f);
            int la = cbase + drow * LCP + dcol;
            float g00 = (float)tile[la];
            float g01 = (float)tile[la + 1];
            float g10 = (float)tile[la + LCP];
            float g11 = (float)tile[la + LCP + 1];
            float top = fmaf(wx, g01 - g00, g00);
            float bot = fmaf(wx, g11 - g10, g10);
            acc = fmaf(af[k], fmaf(wy, bot - top, top), acc);
        }

        float feat = (dd > 0.f) ? dd : acc;
        if (LAST) out[p] = feat;
        else      planeOut[p] = (_Float16)(feat * cf);
    }
}

// ---------------------------------------------------------------------------
// fallback (round-1 style) if workspace is too small
// ---------------------------------------------------------------------------
__global__ __launch_bounds__(256) void nlspn_init_kernel(
    const float* __restrict__ pred,
    const float* __restrict__ conf,
    float* __restrict__ ff)
{
    int p = blockIdx.x * blockDim.x + threadIdx.x;
    if (p < NPIX) ff[p] = pred[p] * conf[p];
}

template <bool LAST>
__global__ __launch_bounds__(256) void nlspn_prop_kernel(
    const float* __restrict__ aff_raw,
    const float* __restrict__ offset,
    const float* __restrict__ conf,
    const float* __restrict__ dep,
    const float* __restrict__ scale,
    const float* __restrict__ ff_in,
    float* __restrict__ out)
{
    int p = blockIdx.x * blockDim.x + threadIdx.x;
    if (p >= NPIX) return;
    int b  = p / HWN;
    int hw = p - b * HWN;
    int h  = hw / WNUM;
    int w  = hw - h * WNUM;

    float s    = scale[0];
    float invs = 1.0f / (s + 1e-8f);

    float a[8];
    const float* ar = aff_raw + (size_t)b * 8 * HWN + hw;
#pragma unroll
    for (int k = 0; k < 8; ++k) a[k] = ar[(size_t)k * HWN];

    float asum = 0.0f;
#pragma unroll
    for (int k = 0; k < 8; ++k) {
        a[k] = fast_tanh(a[k]) * invs;
        asum += fabsf(a[k]);
    }
    asum += 1e-4f;
    float rden = 1.0f / fmaxf(asum, 1.0f);
    float suma = 0.0f;
#pragma unroll
    for (int k = 0; k < 8; ++k) { a[k] *= rden; suma += a[k]; }
    float aref = 1.0f - suma;

    const float* ffb = ff_in + (size_t)b * HWN;
    float acc = aref * ffb[hw];

    const float* off = offset + (size_t)b * 16 * HWN + hw;
#pragma unroll
    for (int k = 0; k < 8; ++k) {
        int   k9 = (k < 4) ? k : k + 1;
        int   dy = k9 / 3 - 1;
        int   dx = k9 - (k9 / 3) * 3 - 1;
        float offy = off[(size_t)(2 * k)     * HWN];
        float offx = off[(size_t)(2 * k + 1) * HWN];
        float ysf = (float)(h + dy) + offy;
        float xsf = (float)(w + dx) + offx;
        float y0f = floorf(ysf);
        float x0f = floorf(xsf);
        float wy  = ysf - y0f;
        float wx  = xsf - x0f;
        int   y0  = (int)y0f;
        int   x0  = (int)x0f;
        bool yv0 = (y0 >= 0)  & (y0 < HNUM);
        bool yv1 = (y0 >= -1) & (y0 + 1 < HNUM);
        bool xv0 = (x0 >= 0)  & (x0 < WNUM);
        bool xv1 = (x0 >= -1) & (x0 + 1 < WNUM);
        int row0 = y0 * WNUM;
        float g00 = 0.f, g01 = 0.f, g10 = 0.f, g11 = 0.f;
        if (yv0 & xv0) g00 = ffb[row0 + x0];
        if (yv0 & xv1) g01 = ffb[row0 + x0 + 1];
        if (yv1 & xv0) g10 = ffb[row0 + WNUM + x0];
        if (yv1 & xv1) g11 = ffb[row0 + WNUM + x0 + 1];
        float sampled = (1.f - wy) * ((1.f - wx) * g00 + wx * g01)
                      +        wy  * ((1.f - wx) * g10 + wx * g11);
        acc += a[k] * sampled;
    }

    float dd   = dep[p];
    float feat = (dd > 0.0f) ? dd : acc;
    if (LAST) out[p] = feat;
    else      out[p] = feat * conf[p];
}

// ---------------------------------------------------------------------------
extern "C" void kernel_launch(void* const* d_in, const int* in_sizes, int n_in,
                              void* d_out, int out_size, void* d_ws, size_t ws_size,
                              hipStream_t stream)
{
    const float* aff_raw = (const float*)d_in[0];
    const float* offset  = (const float*)d_in[1];
    const float* conf    = (const float*)d_in[2];
    const float* pred    = (const float*)d_in[3];
    const float* dep     = (const float*)d_in[4];
    const float* scale   = (const float*)d_in[5];
    float* out = (float*)d_out;

    const int threads = 256;
    const size_t need = (size_t)NPIX * 48 + (size_t)NPIX * 2 * 2 + 64;

    if (ws_size >= need) {
        char* wb = (char*)d_ws;
        uint4* tapsA  = (uint4*)wb;  wb += (size_t)NPIX * 16;
        uint4* tapsB  = (uint4*)wb;  wb += (size_t)NPIX * 16;
        uint4* affaux = (uint4*)wb;  wb += (size_t)NPIX * 16;
        _Float16* plA = (_Float16*)wb;  wb += (size_t)NPIX * 2;
        _Float16* plB = (_Float16*)wb;

        nlspn_step1_lds<<<NTILE, threads, 0, stream>>>(
            aff_raw, offset, conf, dep, pred, scale,
            plB, tapsA, tapsB, affaux);                                     // ff1 -> B
        nlspn_prop_lds<false><<<NTILE, threads, 0, stream>>>(
            tapsA, tapsB, affaux, plB, plA, out);                           // ff2 -> A
        nlspn_prop_lds<false><<<NTILE, threads, 0, stream>>>(
            tapsA, tapsB, affaux, plA, plB, out);                           // ff3 -> B
        nlspn_prop_lds<false><<<NTILE, threads, 0, stream>>>(
            tapsA, tapsB, affaux, plB, plA, out);                           // ff4 -> A
        nlspn_prop_lds<false><<<NTILE, threads, 0, stream>>>(
            tapsA, tapsB, affaux, plA, plB, out);                           // ff5 -> B
        nlspn_prop_lds<true><<<NTILE, threads, 0, stream>>>(
            tapsA, tapsB, affaux, plB, plA, out);                           // feat6 -> d_out
    } else {
        const int blocksP = (NPIX + threads - 1) / threads;
        float* ws = (float*)d_ws;
        nlspn_init_kernel<<<blocksP, threads, 0, stream>>>(pred, conf, out);
        nlspn_prop_kernel<false><<<blocksP, threads, 0, stream>>>(aff_raw, offset, conf, dep, scale, out, ws);
        nlspn_prop_kernel<false><<<blocksP, threads, 0, stream>>>(aff_raw, offset, conf, dep, scale, ws, out);
        nlspn_prop_kernel<false><<<blocksP, threads, 0, stream>>>(aff_raw, offset, conf, dep, scale, out, ws);
        nlspn_prop_kernel<false><<<blocksP, threads, 0, stream>>>(aff_raw, offset, conf, dep, scale, ws, out);
        nlspn_prop_kernel<false><<<blocksP, threads, 0, stream>>>(aff_raw, offset, conf, dep, scale, out, ws);
        nlspn_prop_kernel<true ><<<blocksP, threads, 0, stream>>>(aff_raw, offset, conf, dep, scale, ws, out);
    }
}

// Round 13
// 112.131 us; speedup vs baseline: 1.2335x; 1.2335x over previous
//
#include <hip/hip_runtime.h>
#include <stdint.h>

#define HNUM 240
#define WNUM 1216
#define BNUM 4
#define HWN (HNUM * WNUM)
#define NPIX (BNUM * HWN)
#define NP2T (NPIX / 2)           /* 583680 threads for meta build */
#define GRIDM (NP2T / 256)        /* 2280 blocks */

/* prop tile */
#define TR 16
#define TC 64
#define RH 8                      /* s4 displacement <= 8 -> halo 8 suffices */
#define LR (TR + 2 * RH + 1)      /* 33 */
#define LC (TC + 2 * RH + 1)      /* 81 */
#define LCP 82                    /* row stride (41 banks offset per row) */
#define LDSN (LR * LCP)           /* 2706 */
#define PXJ 4
#define TGR (HNUM / TR)           /* 15 */
#define TGC (WNUM / TC)           /* 19 */
#define NTILE (BNUM * TGR * TGC)  /* 1140 */

union HCV { uint32_t u; _Float16 h[2]; };

__device__ __forceinline__ float fast_tanh(float x) {
    float ax = fabsf(x);
    float e  = __builtin_amdgcn_exp2f(ax * 2.885390081777927f);  // 2*log2(e)
    float t  = 1.0f - 2.0f * __builtin_amdgcn_rcpf(e + 1.0f);
    return copysignf(t, x);
}

// ---------------------------------------------------------------------------
// meta build (pure streaming, no LDS): 2 px/thread, float2 loads.
// tap u32 = drow s4 | dcol s4 | qy u8 <<8 | qx u8 <<16 | aff s8 <<24
// aux uint2 = { half2(aref, conf), dep f32 }.  Also writes ff0 = pred*conf.
// ---------------------------------------------------------------------------
__global__ __launch_bounds__(256) void nlspn_meta_build(
    const float* __restrict__ aff_raw,
    const float* __restrict__ offset,
    const float* __restrict__ conf,
    const float* __restrict__ dep,
    const float* __restrict__ pred,
    const float* __restrict__ scale,
    _Float16* __restrict__ plane0,
    uint4* __restrict__ tapsA,
    uint4* __restrict__ tapsB,
    uint2* __restrict__ auxv)
{
    int t = blockIdx.x * 256 + (int)threadIdx.x;   // < NP2T exactly
    int p0 = 2 * t;
    int b  = p0 / HWN;
    int hw = p0 - b * HWN;
    int h  = hw / WNUM;
    int w0 = hw - h * WNUM;                        // even; pair same row

    float s    = scale[0];
    float invs = 1.0f / (s + 1e-8f);

    const float* arb = aff_raw + (size_t)b * 8 * HWN + hw;
    const float* ofb = offset  + (size_t)b * 16 * HWN + hw;

    float2 ar2[8], oy2[8], ox2[8];
#pragma unroll
    for (int k = 0; k < 8; ++k)
        ar2[k] = *(const float2*)(arb + (size_t)k * HWN);
#pragma unroll
    for (int k = 0; k < 8; ++k) {
        oy2[k] = *(const float2*)(ofb + (size_t)(2 * k)     * HWN);
        ox2[k] = *(const float2*)(ofb + (size_t)(2 * k + 1) * HWN);
    }
    float2 cf2 = *(const float2*)(conf + p0);
    float2 dd2 = *(const float2*)(dep  + p0);
    float2 pp2 = *(const float2*)(pred + p0);

    _Float16 plo[2];

#pragma unroll
    for (int jj = 0; jj < 2; ++jj) {
        int w = w0 + jj;
        float cf = (jj == 0) ? cf2.x : cf2.y;
        float dd = (jj == 0) ? dd2.x : dd2.y;
        float pp = (jj == 0) ? pp2.x : pp2.y;

        // affinity normalization
        float aa[8];
        float asum = 0.f;
#pragma unroll
        for (int k = 0; k < 8; ++k) {
            float rv = (jj == 0) ? ar2[k].x : ar2[k].y;
            float v  = fast_tanh(rv) * invs;
            aa[k] = v;
            asum += fabsf(v);
        }
        float rden = 1.0f / fmaxf(asum + 1e-4f, 1.0f);
        float sm = 0.f;
#pragma unroll
        for (int k = 0; k < 8; ++k) { aa[k] *= rden; sm += aa[k]; }
        float aref = 1.0f - sm;

        // taps (aff s8 embedded)
        uint32_t tw[8];
#pragma unroll
        for (int k = 0; k < 8; ++k) {
            int k9 = (k < 4) ? k : k + 1;
            int dy = k9 / 3 - 1;
            int dx = k9 - (k9 / 3) * 3 - 1;
            float offy = (jj == 0) ? oy2[k].x : oy2[k].y;
            float offx = (jj == 0) ? ox2[k].x : ox2[k].y;
            float ys  = (float)(h + dy) + offy;
            float xs  = (float)(w + dx) + offx;
            float y0f = floorf(ys), x0f = floorf(xs);
            float wyf = ys - y0f,   wxf = xs - x0f;
            int y0 = (int)y0f;
            int x0 = (int)x0f;
            int drow = y0 - h;
            int dcol = x0 - w;
            uint32_t qy = (uint32_t)(wyf * 255.0f + 0.5f); if (qy > 255) qy = 255;
            uint32_t qx = (uint32_t)(wxf * 255.0f + 0.5f); if (qx > 255) qx = 255;
            float av = aa[k];
            bool ok = (y0 >= -1) & (y0 <= HNUM) & (x0 >= -1) & (x0 <= WNUM)
                    & (drow >= -8) & (drow <= 7) & (dcol >= -8) & (dcol <= 7);
            if (!ok) { drow = 0; dcol = 0; qy = 0; qx = 0; av = 0.f; }
            int q8 = (int)floorf(av * 127.0f + 0.5f);
            q8 = (q8 < -127) ? -127 : ((q8 > 127) ? 127 : q8);
            tw[k] = ((uint32_t)drow & 0xfu)
                  | (((uint32_t)dcol & 0xfu) << 4)
                  | (qy << 8) | (qx << 16)
                  | ((uint32_t)(uint8_t)(int8_t)q8 << 24);
        }

        tapsA[p0 + jj] = make_uint4(tw[0], tw[1], tw[2], tw[3]);
        tapsB[p0 + jj] = make_uint4(tw[4], tw[5], tw[6], tw[7]);

        HCV cv;
        cv.h[0] = (_Float16)aref;
        cv.h[1] = (_Float16)cf;
        auxv[p0 + jj] = make_uint2(cv.u, __float_as_uint(dd));

        plo[jj] = (_Float16)(pp * cf);
    }

    HCV pv;
    pv.h[0] = plo[0];
    pv.h[1] = plo[1];
    *(uint32_t*)(plane0 + p0) = pv.u;
}

// ---------------------------------------------------------------------------
// propagation step: plane tile in LDS (halo 8), 33 LDS gathers/px
// ---------------------------------------------------------------------------
template <bool LAST>
__global__ __launch_bounds__(256) void nlspn_prop_lds(
    const uint4* __restrict__ tapsA,
    const uint4* __restrict__ tapsB,
    const uint2* __restrict__ auxv,
    const _Float16* __restrict__ planeIn,
    _Float16* __restrict__ planeOut,
    float* __restrict__ out)
{
    __shared__ _Float16 tile[LDSN];

    int bid  = blockIdx.x;
    int b    = bid / (TGR * TGC);
    int rem  = bid - b * (TGR * TGC);
    int tr   = rem / TGC;
    int tc   = rem - tr * TGC;
    int tid  = (int)threadIdx.x;
    int lane = tid & 63;
    int wrow = tid >> 6;

    int row0 = tr * TR - RH;
    int col0 = tc * TC - RH;
    const _Float16* pb = planeIn + (size_t)b * HWN;

    for (int i = tid; i < LDSN; i += 256) {
        int lr = i / LCP;
        int lc = i - lr * LCP;
        int gr = row0 + lr;
        int gc = col0 + lc;
        _Float16 v = (_Float16)0.f;
        if (lc < LC && gr >= 0 && gr < HNUM && gc >= 0 && gc < WNUM)
            v = pb[gr * WNUM + gc];
        tile[i] = v;
    }
    __syncthreads();

#pragma unroll
    for (int j = 0; j < PXJ; ++j) {
        int rj = wrow * PXJ + j;
        int h  = tr * TR + rj;
        int w  = tc * TC + lane;
        int p  = b * HWN + h * WNUM + w;

        uint4 tA = tapsA[p];
        uint4 tB = tapsB[p];
        uint2 ax = auxv[p];

        HCV cv; cv.u = ax.x;
        float aref = (float)cv.h[0];
        float cf   = (float)cv.h[1];
        float dd   = __uint_as_float(ax.y);

        int cbase = (RH + rj) * LCP + (RH + lane);
        float acc = aref * (float)tile[cbase];

        uint32_t tm[8] = {tA.x, tA.y, tA.z, tA.w, tB.x, tB.y, tB.z, tB.w};
#pragma unroll
        for (int k = 0; k < 8; ++k) {
            uint32_t m = tm[k];
            int drow = ((int)(m << 28)) >> 28;
            int dcol = ((int)(m << 24)) >> 28;
            float wy = (float)((m >> 8)  & 0xffu) * (1.0f / 255.0f);
            float wx = (float)((m >> 16) & 0xffu) * (1.0f / 255.0f);
            float af = (float)((int)m >> 24) * (1.0f / 127.0f);
            int la = cbase + drow * LCP + dcol;
            float g00 = (float)tile[la];
            float g01 = (float)tile[la + 1];
            float g10 = (float)tile[la + LCP];
            float g11 = (float)tile[la + LCP + 1];
            float top = fmaf(wx, g01 - g00, g00);
            float bot = fmaf(wx, g11 - g10, g10);
            acc = fmaf(af, fmaf(wy, bot - top, top), acc);
        }

        float feat = (dd > 0.f) ? dd : acc;
        if (LAST) out[p] = feat;
        else      planeOut[p] = (_Float16)(feat * cf);
    }
}

// ---------------------------------------------------------------------------
// fallback (round-1 style) if workspace is too small
// ---------------------------------------------------------------------------
__global__ __launch_bounds__(256) void nlspn_init_kernel(
    const float* __restrict__ pred,
    const float* __restrict__ conf,
    float* __restrict__ ff)
{
    int p = blockIdx.x * blockDim.x + threadIdx.x;
    if (p < NPIX) ff[p] = pred[p] * conf[p];
}

template <bool LAST>
__global__ __launch_bounds__(256) void nlspn_prop_kernel(
    const float* __restrict__ aff_raw,
    const float* __restrict__ offset,
    const float* __restrict__ conf,
    const float* __restrict__ dep,
    const float* __restrict__ scale,
    const float* __restrict__ ff_in,
    float* __restrict__ out)
{
    int p = blockIdx.x * blockDim.x + threadIdx.x;
    if (p >= NPIX) return;
    int b  = p / HWN;
    int hw = p - b * HWN;
    int h  = hw / WNUM;
    int w  = hw - h * WNUM;

    float s    = scale[0];
    float invs = 1.0f / (s + 1e-8f);

    float a[8];
    const float* ar = aff_raw + (size_t)b * 8 * HWN + hw;
#pragma unroll
    for (int k = 0; k < 8; ++k) a[k] = ar[(size_t)k * HWN];

    float asum = 0.0f;
#pragma unroll
    for (int k = 0; k < 8; ++k) {
        a[k] = fast_tanh(a[k]) * invs;
        asum += fabsf(a[k]);
    }
    asum += 1e-4f;
    float rden = 1.0f / fmaxf(asum, 1.0f);
    float suma = 0.0f;
#pragma unroll
    for (int k = 0; k < 8; ++k) { a[k] *= rden; suma += a[k]; }
    float aref = 1.0f - suma;

    const float* ffb = ff_in + (size_t)b * HWN;
    float acc = aref * ffb[hw];

    const float* off = offset + (size_t)b * 16 * HWN + hw;
#pragma unroll
    for (int k = 0; k < 8; ++k) {
        int   k9 = (k < 4) ? k : k + 1;
        int   dy = k9 / 3 - 1;
        int   dx = k9 - (k9 / 3) * 3 - 1;
        float offy = off[(size_t)(2 * k)     * HWN];
        float offx = off[(size_t)(2 * k + 1) * HWN];
        float ysf = (float)(h + dy) + offy;
        float xsf = (float)(w + dx) + offx;
        float y0f = floorf(ysf);
        float x0f = floorf(xsf);
        float wy  = ysf - y0f;
        float wx  = xsf - x0f;
        int   y0  = (int)y0f;
        int   x0  = (int)x0f;
        bool yv0 = (y0 >= 0)  & (y0 < HNUM);
        bool yv1 = (y0 >= -1) & (y0 + 1 < HNUM);
        bool xv0 = (x0 >= 0)  & (x0 < WNUM);
        bool xv1 = (x0 >= -1) & (x0 + 1 < WNUM);
        int row0 = y0 * WNUM;
        float g00 = 0.f, g01 = 0.f, g10 = 0.f, g11 = 0.f;
        if (yv0 & xv0) g00 = ffb[row0 + x0];
        if (yv0 & xv1) g01 = ffb[row0 + x0 + 1];
        if (yv1 & xv0) g10 = ffb[row0 + WNUM + x0];
        if (yv1 & xv1) g11 = ffb[row0 + WNUM + x0 + 1];
        float sampled = (1.f - wy) * ((1.f - wx) * g00 + wx * g01)
                      +        wy  * ((1.f - wx) * g10 + wx * g11);
        acc += a[k] * sampled;
    }

    float dd   = dep[p];
    float feat = (dd > 0.0f) ? dd : acc;
    if (LAST) out[p] = feat;
    else      out[p] = feat * conf[p];
}

// ---------------------------------------------------------------------------
extern "C" void kernel_launch(void* const* d_in, const int* in_sizes, int n_in,
                              void* d_out, int out_size, void* d_ws, size_t ws_size,
                              hipStream_t stream)
{
    const float* aff_raw = (const float*)d_in[0];
    const float* offset  = (const float*)d_in[1];
    const float* conf    = (const float*)d_in[2];
    const float* pred    = (const float*)d_in[3];
    const float* dep     = (const float*)d_in[4];
    const float* scale   = (const float*)d_in[5];
    float* out = (float*)d_out;

    const int threads = 256;
    const size_t need = (size_t)NPIX * 44 + 64;

    if (ws_size >= need) {
        char* wb = (char*)d_ws;
        uint4* tapsA  = (uint4*)wb;  wb += (size_t)NPIX * 16;
        uint4* tapsB  = (uint4*)wb;  wb += (size_t)NPIX * 16;
        uint2* auxv   = (uint2*)wb;  wb += (size_t)NPIX * 8;
        _Float16* plA = (_Float16*)wb;  wb += (size_t)NPIX * 2;
        _Float16* plB = (_Float16*)wb;

        nlspn_meta_build<<<GRIDM, threads, 0, stream>>>(
            aff_raw, offset, conf, dep, pred, scale,
            plA, tapsA, tapsB, auxv);                                       // ff0 -> A
        nlspn_prop_lds<false><<<NTILE, threads, 0, stream>>>(
            tapsA, tapsB, auxv, plA, plB, out);                             // ff1 -> B
        nlspn_prop_lds<false><<<NTILE, threads, 0, stream>>>(
            tapsA, tapsB, auxv, plB, plA, out);                             // ff2 -> A
        nlspn_prop_lds<false><<<NTILE, threads, 0, stream>>>(
            tapsA, tapsB, auxv, plA, plB, out);                             // ff3 -> B
        nlspn_prop_lds<false><<<NTILE, threads, 0, stream>>>(
            tapsA, tapsB, auxv, plB, plA, out);                             // ff4 -> A
        nlspn_prop_lds<false><<<NTILE, threads, 0, stream>>>(
            tapsA, tapsB, auxv, plA, plB, out);                             // ff5 -> B
        nlspn_prop_lds<true><<<NTILE, threads, 0, stream>>>(
            tapsA, tapsB, auxv, plB, plA, out);                             // feat6 -> d_out
    } else {
        const int blocksP = (NPIX + threads - 1) / threads;
        float* ws = (float*)d_ws;
        nlspn_init_kernel<<<blocksP, threads, 0, stream>>>(pred, conf, out);
        nlspn_prop_kernel<false><<<blocksP, threads, 0, stream>>>(aff_raw, offset, conf, dep, scale, out, ws);
        nlspn_prop_kernel<false><<<blocksP, threads, 0, stream>>>(aff_raw, offset, conf, dep, scale, ws, out);
        nlspn_prop_kernel<false><<<blocksP, threads, 0, stream>>>(aff_raw, offset, conf, dep, scale, out, ws);
        nlspn_prop_kernel<false><<<blocksP, threads, 0, stream>>>(aff_raw, offset, conf, dep, scale, ws, out);
        nlspn_prop_kernel<false><<<blocksP, threads, 0, stream>>>(aff_raw, offset, conf, dep, scale, out, ws);
        nlspn_prop_kernel<true ><<<blocksP, threads, 0, stream>>>(aff_raw, offset, conf, dep, scale, ws, out);
    }
}